// Round 1
// baseline (623.901 us; speedup 1.0000x reference)
//
#include <hip/hip_runtime.h>
#include <hip/hip_fp16.h>

#define N_NODES 100000
#define EDGES   1600000
#define D       128
#define BN_EPS  1e-5f
#define TM      64                        // rows per GEMM block
#define NB      ((N_NODES + 255) >> 8)    // 391 coarse buckets (256 nodes each)
#define L1E     16                        // slots per thread in partition pass
#define L1TILE  (256 * L1E)               // 4096 slots per tile

// src-blocking for the gather sweep
#define SBS     13                        // src blocks: src>>13 in [0,12] (8192 nodes = 2MB fp16)
#define KPW     13                        // nodes owned per wave (acc in regs: 26 VGPR)
#define NW      ((N_NODES + KPW - 1) / KPW)   // 7693 waves
#define GBLK    ((NW + 3) / 4)                // 1924 blocks, all resident

typedef __attribute__((ext_vector_type(8))) short short8;
typedef __attribute__((ext_vector_type(4))) float f32x4;

__device__ __forceinline__ unsigned short bf_hi(float f) {
    unsigned u = __float_as_uint(f);
    unsigned t = u + 0x7FFF + ((u >> 16) & 1);
    return (unsigned short)(t >> 16);
}
__device__ __forceinline__ float bf_val(unsigned short h) {
    return __uint_as_float(((unsigned)h) << 16);
}

// ---------------------------------------------------------------------------
// K0: convert x -> fp16 mirror (in d_out scratch); zero stats(512f)+bsum(512i)
// ---------------------------------------------------------------------------
__global__ void convert_zero(const float* __restrict__ x, __half* __restrict__ xh,
                             int* __restrict__ zbase) {
    int gid = blockIdx.x * blockDim.x + threadIdx.x;
    if (gid < 1024) zbase[gid] = 0;
    const int n4 = N_NODES * (D / 4);
    if (gid < n4) {
        float4 v = ((const float4*)x)[gid];
        __half2 h0 = __float22half2_rn(make_float2(v.x, v.y));
        __half2 h1 = __float22half2_rn(make_float2(v.z, v.w));
        ((__half2*)xh)[(long long)gid * 2 + 0] = h0;
        ((__half2*)xh)[(long long)gid * 2 + 1] = h1;
    }
}

// ---------------------------------------------------------------------------
// K1: bucket-level histogram: LDS 391 counters/tile, 1 global atomic per
// (tile,bucket)
// ---------------------------------------------------------------------------
__launch_bounds__(256)
__global__ void bucket_count(const int* __restrict__ ei, int* __restrict__ bsum) {
    __shared__ int cnt[NB];
    const int tid = threadIdx.x;
    for (int i = tid; i < NB; i += 256) cnt[i] = 0;
    __syncthreads();
    const int t0 = blockIdx.x * L1TILE + tid;
#pragma unroll
    for (int j = 0; j < L1E; ++j) {
        int t = t0 + j * 256;
        if (t < 2 * EDGES) {
            int pt = (t < EDGES) ? t + EDGES : t - EDGES;
            atomicAdd(&cnt[ei[pt] >> 8], 1);
        }
    }
    __syncthreads();
    for (int i = tid; i < NB; i += 256) {
        int c = cnt[i];
        if (c) atomicAdd(&bsum[i], c);
    }
}

// ---------------------------------------------------------------------------
// K2: exclusive scan of 391 bucket sums -> bbase (NB+1), seed gcur
// ---------------------------------------------------------------------------
__global__ void scan_bsums(const int* __restrict__ bsum, int* __restrict__ bbase,
                           int* __restrict__ gcur) {
    __shared__ int s[512];
    const int t = threadIdx.x;
    s[t] = (t < NB) ? bsum[t] : 0;
    __syncthreads();
    for (int d = 1; d < 512; d <<= 1) {
        int u = (t >= d) ? s[t - d] : 0;
        __syncthreads();
        s[t] += u;
        __syncthreads();
    }
    if (t < NB) {
        int e = (t > 0) ? s[t - 1] : 0;
        bbase[t] = e;
        gcur[t] = e;
    }
    if (t == 0) bbase[NB] = 2 * EDGES;
}

// ---------------------------------------------------------------------------
// K2d: split W1/W2 into bf16 hi/lo
// ---------------------------------------------------------------------------
__global__ void split_w(const float* __restrict__ W1, const float* __restrict__ W2,
                        unsigned short* __restrict__ w1h, unsigned short* __restrict__ w1l,
                        unsigned short* __restrict__ w2h, unsigned short* __restrict__ w2l) {
    int i = blockIdx.x * blockDim.x + threadIdx.x;
    if (i < 16384) {
        float f = W1[i];
        unsigned short h = bf_hi(f);
        w1h[i] = h;
        w1l[i] = bf_hi(f - bf_val(h));
    } else if (i < 32768) {
        int j = i - 16384;
        float f = W2[j];
        unsigned short h = bf_hi(f);
        w2h[j] = h;
        w2l[j] = bf_hi(f - bf_val(h));
    }
}

// ---------------------------------------------------------------------------
// K3a: coarse-bucket partition; pairs packed: (local_dst<<17) | src
// (src < 2^17 since N=100000; local_dst = dst & 255)
// ---------------------------------------------------------------------------
__launch_bounds__(256)
__global__ void partition_pairs(const int* __restrict__ ei, int* __restrict__ gcur,
                                int* __restrict__ pairs) {
    __shared__ int cnt[NB];
    __shared__ int cbase[NB];
    const int tid = threadIdx.x;
    for (int i = tid; i < NB; i += 256) cnt[i] = 0;
    __syncthreads();

    int bb[L1E], rr[L1E], pk[L1E];
    const int t0 = blockIdx.x * L1TILE + tid;
#pragma unroll
    for (int j = 0; j < L1E; ++j) {
        int t = t0 + j * 256;
        bb[j] = -1;
        if (t < 2 * EDGES) {
            int vl = ei[t];
            int pt = (t < EDGES) ? t + EDGES : t - EDGES;
            int nd = ei[pt];
            bb[j] = nd >> 8;
            pk[j] = ((nd & 255) << 17) | vl;
            rr[j] = atomicAdd(&cnt[bb[j]], 1);
        }
    }
    __syncthreads();
    for (int i = tid; i < NB; i += 256) {
        int c = cnt[i];
        cbase[i] = c ? atomicAdd(&gcur[i], c) : 0;
    }
    __syncthreads();
#pragma unroll
    for (int j = 0; j < L1E; ++j) {
        if (bb[j] >= 0) pairs[cbase[bb[j]] + rr[j]] = pk[j];
    }
}

// ---------------------------------------------------------------------------
// K3b: per-bucket: count per (node, src-block) in LDS, scan -> off2 segment
// starts, place adj ordered by (node, src-block)
// off2 layout: [node][14] — entries 0..12 = segment starts, 13 = node end
// ---------------------------------------------------------------------------
__launch_bounds__(256)
__global__ void bucket_fill(const int* __restrict__ pairs, const int* __restrict__ bbase,
                            int* __restrict__ off2, int* __restrict__ adj) {
    __shared__ int cnt2[256 * SBS];   // 13.3 KB
    __shared__ int lc[256];
    const int b   = blockIdx.x;
    const int n0  = b << 8;
    const int tid = threadIdx.x;
    const int s0 = bbase[b];
    const int s1 = bbase[b + 1];
    for (int i = tid; i < 256 * SBS; i += 256) cnt2[i] = 0;
    __syncthreads();
    // pass 1: per (node, src-block) counts
    for (int i = s0 + tid; i < s1; i += 256) {
        int p = pairs[i];
        atomicAdd(&cnt2[(p >> 17) * SBS + ((p & 0x1FFFF) >> 13)], 1);
    }
    __syncthreads();
    // per-node totals
    int s = 0;
#pragma unroll
    for (int j = 0; j < SBS; ++j) s += cnt2[tid * SBS + j];
    lc[tid] = s;
    __syncthreads();
    // inclusive scan over 256 node totals
    for (int d = 1; d < 256; d <<= 1) {
        int u = (tid >= d) ? lc[tid - d] : 0;
        __syncthreads();
        lc[tid] += u;
        __syncthreads();
    }
    int run = s0 + lc[tid] - s;                 // node base (exclusive)
    const int n = n0 + tid;
    const bool vn = (n < N_NODES);
    // sequential scan over this node's 13 block-counts; emit starts
#pragma unroll
    for (int j = 0; j < SBS; ++j) {
        int c = cnt2[tid * SBS + j];
        cnt2[tid * SBS + j] = run;              // becomes placement cursor
        if (vn) off2[n * 14 + j] = run;
        run += c;
    }
    if (vn) off2[n * 14 + SBS] = run;           // node end
    __syncthreads();
    // pass 2: place
    for (int i = s0 + tid; i < s1; i += 256) {
        int p = pairs[i];
        int src = p & 0x1FFFF;
        int r = atomicAdd(&cnt2[(p >> 17) * SBS + (src >> 13)], 1);
        adj[r] = src;
    }
}

// ---------------------------------------------------------------------------
// K4: persistent src-blocked gather-aggregate. Every resident wave owns KPW
// nodes (acc in regs); all waves sweep src blocks 0..12 in the same order so
// each XCD's L2 holds the current 2MB block. Emits split-bf16 h_pre.
// ---------------------------------------------------------------------------
__launch_bounds__(256, 8)
__global__ void gather_aggr(const float* __restrict__ x, const __half* __restrict__ xh,
                            const int* __restrict__ adj, const int* __restrict__ off2,
                            const float* __restrict__ eps_p,
                            unsigned int* __restrict__ hh, unsigned int* __restrict__ hl) {
    const int wave = blockIdx.x * 4 + (threadIdx.x >> 6);
    if (wave >= NW) return;
    const int lane = threadIdx.x & 63;
    const int nbase = __builtin_amdgcn_readfirstlane(wave * KPW);
    const __half2* __restrict__ xp = (const __half2*)xh;

    float2 acc[KPW];
#pragma unroll
    for (int k = 0; k < KPW; ++k) acc[k] = make_float2(0.f, 0.f);

    for (int b = 0; b < SBS; ++b) {
#pragma unroll
        for (int k = 0; k < KPW; ++k) {
            int n = nbase + k;
            if (n < N_NODES) {
                int u = n * 14 + b;
                int st = off2[u];
                int en = off2[u + 1];
                for (int i = st; i < en; i += 4) {
                    // a0,a1 loads unconditional (adj padded by 4 ints)
                    int a0 = adj[i];
                    int a1 = adj[i + 1];
                    {
                        __half2 v = xp[(unsigned)a0 * 64u + (unsigned)lane];
                        acc[k].x += __low2float(v);
                        acc[k].y += __high2float(v);
                    }
                    if (i + 1 < en) {
                        __half2 v = xp[(unsigned)a1 * 64u + (unsigned)lane];
                        acc[k].x += __low2float(v);
                        acc[k].y += __high2float(v);
                    }
                    if (i + 2 < en) {
                        int a2 = adj[i + 2];
                        __half2 v = xp[(unsigned)a2 * 64u + (unsigned)lane];
                        acc[k].x += __low2float(v);
                        acc[k].y += __high2float(v);
                    }
                    if (i + 3 < en) {
                        int a3 = adj[i + 3];
                        __half2 v = xp[(unsigned)a3 * 64u + (unsigned)lane];
                        acc[k].x += __low2float(v);
                        acc[k].y += __high2float(v);
                    }
                }
            }
        }
    }

    const float sc = 2.0f + eps_p[0];
#pragma unroll
    for (int k = 0; k < KPW; ++k) {
        int n = nbase + k;
        if (n < N_NODES) {
            float2 xs = ((const float2*)x)[(unsigned)n * 64u + (unsigned)lane];
            float ox = fmaf(sc, xs.x, acc[k].x);
            float oy = fmaf(sc, xs.y, acc[k].y);
            unsigned short hx = bf_hi(ox), hy = bf_hi(oy);
            unsigned short lx = bf_hi(ox - bf_val(hx)), ly = bf_hi(oy - bf_val(hy));
            hh[(unsigned)n * 64u + lane] = (unsigned)hx | ((unsigned)hy << 16);
            hl[(unsigned)n * 64u + lane] = (unsigned)lx | ((unsigned)ly << 16);
        }
    }
}

// ---------------------------------------------------------------------------
// K5: h1 = h_pre @ W1^T + b1 (MFMA split-bf16, fp32-accurate) + BN stats
// ---------------------------------------------------------------------------
__launch_bounds__(256)
__global__ void gemm1_mfma(const unsigned short* __restrict__ hh,
                           const unsigned short* __restrict__ hl,
                           const unsigned short* __restrict__ w1h,
                           const unsigned short* __restrict__ w1l,
                           const float* __restrict__ b1, float* __restrict__ h1,
                           float* __restrict__ stats) {
    __shared__ unsigned short sH[TM][136];
    __shared__ unsigned short sL[TM][136];
    __shared__ float sPart[2][4][128];
    const int tid = threadIdx.x;
    const int wv  = tid >> 6;
    const int ln  = tid & 63;
    const int lc  = ln & 15;
    const int qd  = ln >> 4;
    const int row0 = blockIdx.x * TM;

#pragma unroll
    for (int i = 0; i < 4; ++i) {
        int f = tid + 256 * i;
        int r = f >> 4, c8 = f & 15;
        int gr = row0 + r;
        uint4 vh = make_uint4(0, 0, 0, 0), vl = make_uint4(0, 0, 0, 0);
        if (gr < N_NODES) {
            vh = *(const uint4*)(hh + (long long)gr * D + c8 * 8);
            vl = *(const uint4*)(hl + (long long)gr * D + c8 * 8);
        }
        *(uint4*)&sH[r][c8 * 8] = vh;
        *(uint4*)&sL[r][c8 * 8] = vl;
    }
    __syncthreads();

    f32x4 acc[8];
#pragma unroll
    for (int t = 0; t < 8; ++t) acc[t] = (f32x4){0.f, 0.f, 0.f, 0.f};

    const int arow = wv * 16 + lc;
#pragma unroll
    for (int kk = 0; kk < 4; ++kk) {
        short8 ah = *(const short8*)&sH[arow][kk * 32 + qd * 8];
        short8 al = *(const short8*)&sL[arow][kk * 32 + qd * 8];
#pragma unroll
        for (int t = 0; t < 8; ++t) {
            const int woff = (t * 16 + lc) * D + kk * 32 + qd * 8;
            short8 bh = *(const short8*)(w1h + woff);
            short8 bl = *(const short8*)(w1l + woff);
            acc[t] = __builtin_amdgcn_mfma_f32_16x16x32_bf16(ah, bh, acc[t], 0, 0, 0);
            acc[t] = __builtin_amdgcn_mfma_f32_16x16x32_bf16(al, bh, acc[t], 0, 0, 0);
            acc[t] = __builtin_amdgcn_mfma_f32_16x16x32_bf16(ah, bl, acc[t], 0, 0, 0);
        }
    }

    float psum[8], psq[8];
#pragma unroll
    for (int t = 0; t < 8; ++t) {
        int col = t * 16 + lc;
        float bb = b1[col];
        float s = 0.f, q = 0.f;
#pragma unroll
        for (int r = 0; r < 4; ++r) {
            int grow = row0 + wv * 16 + qd * 4 + r;
            if (grow < N_NODES) {
                float o = acc[t][r] + bb;
                h1[(long long)grow * D + col] = o;
                s += o;
                q += o * o;
            }
        }
        psum[t] = s; psq[t] = q;
    }
#pragma unroll
    for (int t = 0; t < 8; ++t) {
        float s = psum[t], q = psq[t];
        s += __shfl_xor(s, 16); s += __shfl_xor(s, 32);
        q += __shfl_xor(q, 16); q += __shfl_xor(q, 32);
        if (qd == 0) { sPart[0][wv][t * 16 + lc] = s; sPart[1][wv][t * 16 + lc] = q; }
    }
    __syncthreads();
    if (tid < 128) {
        float s = sPart[0][0][tid] + sPart[0][1][tid] + sPart[0][2][tid] + sPart[0][3][tid];
        float q = sPart[1][0][tid] + sPart[1][1][tid] + sPart[1][2][tid] + sPart[1][3][tid];
        atomicAdd(&stats[tid], s);
        atomicAdd(&stats[128 + tid], q);
    }
}

// ---------------------------------------------------------------------------
// K6: out = relu(bn(h1)) @ W2^T + b2  (MFMA split-bf16), in-place on d_out
// ---------------------------------------------------------------------------
__launch_bounds__(256)
__global__ void gemm2_mfma(float* __restrict__ h1out,
                           const unsigned short* __restrict__ w2h,
                           const unsigned short* __restrict__ w2l,
                           const float* __restrict__ b2, const float* __restrict__ stats,
                           const float* __restrict__ gamma, const float* __restrict__ beta) {
    __shared__ unsigned short sH[TM][136];
    __shared__ unsigned short sL[TM][136];
    __shared__ float sScale[128];
    __shared__ float sShift[128];
    const int tid = threadIdx.x;
    const int wv  = tid >> 6;
    const int ln  = tid & 63;
    const int lc  = ln & 15;
    const int qd  = ln >> 4;
    const int row0 = blockIdx.x * TM;

    if (tid < 128) {
        float mean = stats[tid] * (1.0f / N_NODES);
        float var  = fmaxf(stats[128 + tid] * (1.0f / N_NODES) - mean * mean, 0.0f);
        float s    = gamma[tid] * rsqrtf(var + BN_EPS);
        sScale[tid] = s;
        sShift[tid] = beta[tid] - mean * s;
    }
    __syncthreads();

#pragma unroll
    for (int i = 0; i < 8; ++i) {
        int f = tid + 256 * i;
        int r = f >> 5, c4 = f & 31;
        int gr = row0 + r;
        float4 v = make_float4(0.f, 0.f, 0.f, 0.f);
        if (gr < N_NODES) {
            v = *(const float4*)(h1out + (long long)gr * D + c4 * 4);
            float4 sc = *(const float4*)&sScale[c4 * 4];
            float4 sh = *(const float4*)&sShift[c4 * 4];
            v.x = fmaxf(0.f, fmaf(v.x, sc.x, sh.x));
            v.y = fmaxf(0.f, fmaf(v.y, sc.y, sh.y));
            v.z = fmaxf(0.f, fmaf(v.z, sc.z, sh.z));
            v.w = fmaxf(0.f, fmaf(v.w, sc.w, sh.w));
        }
        unsigned short h0 = bf_hi(v.x), h1b = bf_hi(v.y), h2 = bf_hi(v.z), h3 = bf_hi(v.w);
        unsigned short l0 = bf_hi(v.x - bf_val(h0)), l1 = bf_hi(v.y - bf_val(h1b));
        unsigned short l2 = bf_hi(v.z - bf_val(h2)), l3 = bf_hi(v.w - bf_val(h3));
        *(uint2*)&sH[r][c4 * 4] = make_uint2((unsigned)h0 | ((unsigned)h1b << 16),
                                             (unsigned)h2 | ((unsigned)h3 << 16));
        *(uint2*)&sL[r][c4 * 4] = make_uint2((unsigned)l0 | ((unsigned)l1 << 16),
                                             (unsigned)l2 | ((unsigned)l3 << 16));
    }
    __syncthreads();

    f32x4 acc[8];
#pragma unroll
    for (int t = 0; t < 8; ++t) acc[t] = (f32x4){0.f, 0.f, 0.f, 0.f};

    const int arow = wv * 16 + lc;
#pragma unroll
    for (int kk = 0; kk < 4; ++kk) {
        short8 ah = *(const short8*)&sH[arow][kk * 32 + qd * 8];
        short8 al = *(const short8*)&sL[arow][kk * 32 + qd * 8];
#pragma unroll
        for (int t = 0; t < 8; ++t) {
            const int woff = (t * 16 + lc) * D + kk * 32 + qd * 8;
            short8 bh = *(const short8*)(w2h + woff);
            short8 bl = *(const short8*)(w2l + woff);
            acc[t] = __builtin_amdgcn_mfma_f32_16x16x32_bf16(ah, bh, acc[t], 0, 0, 0);
            acc[t] = __builtin_amdgcn_mfma_f32_16x16x32_bf16(al, bh, acc[t], 0, 0, 0);
            acc[t] = __builtin_amdgcn_mfma_f32_16x16x32_bf16(ah, bl, acc[t], 0, 0, 0);
        }
    }

#pragma unroll
    for (int t = 0; t < 8; ++t) {
        int col = t * 16 + lc;
        float bb = b2[col];
#pragma unroll
        for (int r = 0; r < 4; ++r) {
            int grow = row0 + wv * 16 + qd * 4 + r;
            if (grow < N_NODES) {
                h1out[(long long)grow * D + col] = acc[t][r] + bb;
            }
        }
    }
}

// ---------------------------------------------------------------------------
extern "C" void kernel_launch(void* const* d_in, const int* in_sizes, int n_in,
                              void* d_out, int out_size, void* d_ws, size_t ws_size,
                              hipStream_t stream) {
    const float* x     = (const float*)d_in[0];
    const int*   ei    = (const int*)d_in[1];
    const float* eps_p = (const float*)d_in[2];
    const float* W1    = (const float*)d_in[3];
    const float* b1    = (const float*)d_in[4];
    const float* gamma = (const float*)d_in[5];
    const float* beta  = (const float*)d_in[6];
    const float* W2    = (const float*)d_in[7];
    const float* b2    = (const float*)d_in[8];

    // workspace layout (~64.3 MB)
    unsigned int* hh  = (unsigned int*)d_ws;                  // N*64 uints: hpre hi
    unsigned int* hl  = hh + (long long)N_NODES * 64;         // hpre lo
    float* stats = (float*)(hl + (long long)N_NODES * 64);    // 512 floats
    int*   bsum  = (int*)(stats + 512);                       // 512 ints (zeroed w/ stats)
    int*   bbase = bsum + 512;                                // NB+1 ints
    int*   gcur  = bbase + 512;                               // NB ints
    unsigned short* w1h = (unsigned short*)(gcur + 512);
    unsigned short* w1l = w1h + 16384;
    unsigned short* w2h = w1l + 16384;
    unsigned short* w2l = w2h + 16384;
    int*   adj   = (int*)(w2l + 16384);                       // 2E + 4 ints (padded)

    float* out   = (float*)d_out;                             // h1 scratch + final out
    __half* xh   = (__half*)d_out;                            // fp16 mirror: d_out[0:25.6MB]
    int*  pairs  = (int*)((char*)d_out + (size_t)N_NODES * 256);           // [25.6:38.4MB]
    int*  off2   = (int*)((char*)d_out + (size_t)N_NODES * 256
                          + (size_t)2 * EDGES * 4);                        // [38.4:44.0MB]

    {   // K0: fp16 convert + zero stats/bsum
        int grid = (N_NODES * (D / 4) + 255) / 256;
        convert_zero<<<grid, 256, 0, stream>>>(x, xh, (int*)stats);
    }
    {   // K1: bucket histogram
        int grid = (2 * EDGES + L1TILE - 1) / L1TILE;
        bucket_count<<<grid, 256, 0, stream>>>(ei, bsum);
    }
    {   // K2: scan bucket sums -> bbase, gcur
        scan_bsums<<<1, 512, 0, stream>>>(bsum, bbase, gcur);
    }
    {   // K2d: split W1/W2 -> bf16 hi/lo
        split_w<<<128, 256, 0, stream>>>(W1, W2, w1h, w1l, w2h, w2l);
    }
    {   // K3a: coarse-bucket partition (packed int pairs)
        int grid = (2 * EDGES + L1TILE - 1) / L1TILE;
        partition_pairs<<<grid, 256, 0, stream>>>(ei, gcur, pairs);
    }
    {   // K3b: per-(node,srcblk) count+scan+place -> off2, adj
        bucket_fill<<<NB, 256, 0, stream>>>(pairs, bbase, off2, adj);
    }
    {   // K4: persistent src-blocked gather-aggregate -> split bf16 h_pre
        gather_aggr<<<GBLK, 256, 0, stream>>>(x, xh, adj, off2, eps_p, hh, hl);
    }
    {   // K5: MFMA GEMM1 + BN stats (h1 -> d_out)
        int grid = (N_NODES + TM - 1) / TM;
        gemm1_mfma<<<grid, 256, 0, stream>>>((const unsigned short*)hh, (const unsigned short*)hl,
                                             w1h, w1l, b1, out, stats);
    }
    {   // K6: BN finalize + ReLU + MFMA GEMM2, in-place on d_out
        int grid = (N_NODES + TM - 1) / TM;
        gemm2_mfma<<<grid, 256, 0, stream>>>(out, w2h, w2l, b2, stats, gamma, beta);
    }
}

// Round 2
// 462.944 us; speedup vs baseline: 1.3477x; 1.3477x over previous
//
#include <hip/hip_runtime.h>
#include <hip/hip_fp16.h>

#define N_NODES 100000
#define EDGES   1600000
#define D       128
#define BN_EPS  1e-5f
#define TM      64                        // rows per GEMM block
#define NB      ((N_NODES + 255) >> 8)    // 391 coarse buckets (256 nodes each)
#define SLOT    9216                      // fixed slot per bucket: mean 8184 + 10 sigma
#define L1E     16                        // slots per thread in partition pass
#define L1TILE  (256 * L1E)               // 4096 edges per tile

typedef __attribute__((ext_vector_type(8))) short short8;
typedef __attribute__((ext_vector_type(4))) float f32x4;

__device__ __forceinline__ unsigned short bf_hi(float f) {
    unsigned u = __float_as_uint(f);
    unsigned t = u + 0x7FFF + ((u >> 16) & 1);
    return (unsigned short)(t >> 16);
}
__device__ __forceinline__ float bf_val(unsigned short h) {
    return __uint_as_float(((unsigned)h) << 16);
}

// ---------------------------------------------------------------------------
// K0: convert x -> fp16 mirror; zero stats(512f)+gcur(512i); split W1/W2
// ---------------------------------------------------------------------------
__global__ void convert_zero(const float* __restrict__ x, __half* __restrict__ xh,
                             int* __restrict__ zbase,
                             const float* __restrict__ W1, const float* __restrict__ W2,
                             unsigned short* __restrict__ w1h, unsigned short* __restrict__ w1l,
                             unsigned short* __restrict__ w2h, unsigned short* __restrict__ w2l) {
    int gid = blockIdx.x * blockDim.x + threadIdx.x;
    if (gid < 1024) zbase[gid] = 0;
    if (gid < 16384) {
        float f = W1[gid];
        unsigned short h = bf_hi(f);
        w1h[gid] = h;
        w1l[gid] = bf_hi(f - bf_val(h));
    } else if (gid < 32768) {
        int j = gid - 16384;
        float f = W2[j];
        unsigned short h = bf_hi(f);
        w2h[j] = h;
        w2l[j] = bf_hi(f - bf_val(h));
    }
    const int n4 = N_NODES * (D / 4);
    if (gid < n4) {
        float4 v = ((const float4*)x)[gid];
        __half2 h0 = __float22half2_rn(make_float2(v.x, v.y));
        __half2 h1 = __float22half2_rn(make_float2(v.z, v.w));
        ((__half2*)xh)[(long long)gid * 2 + 0] = h0;
        ((__half2*)xh)[(long long)gid * 2 + 1] = h1;
    }
}

// ---------------------------------------------------------------------------
// K3a: coarse-bucket partition into fixed slots (no pre-histogram needed).
// pairs entry: (local_dst<<17) | src   (src < 2^17, local_dst < 256)
// ---------------------------------------------------------------------------
__launch_bounds__(256)
__global__ void partition_pairs(const int* __restrict__ ei, int* __restrict__ gcur,
                                int* __restrict__ pairs) {
    __shared__ int cnt[NB];
    __shared__ int cbase[NB];
    const int tid = threadIdx.x;
    for (int i = tid; i < NB; i += 256) cnt[i] = 0;
    __syncthreads();

    int bb[L1E], rr[L1E], pk[L1E];
    const int t0 = blockIdx.x * L1TILE + tid;
#pragma unroll
    for (int j = 0; j < L1E; ++j) {
        int t = t0 + j * 256;
        bb[j] = -1;
        if (t < 2 * EDGES) {
            int vl = ei[t];
            int pt = (t < EDGES) ? t + EDGES : t - EDGES;
            int nd = ei[pt];
            bb[j] = nd >> 8;
            pk[j] = ((nd & 255) << 17) | vl;
            rr[j] = atomicAdd(&cnt[bb[j]], 1);
        }
    }
    __syncthreads();
    for (int i = tid; i < NB; i += 256) {
        int c = cnt[i];
        cbase[i] = c ? (i * SLOT + atomicAdd(&gcur[i], c)) : 0;
    }
    __syncthreads();
#pragma unroll
    for (int j = 0; j < L1E; ++j) {
        if (bb[j] >= 0) pairs[cbase[bb[j]] + rr[j]] = pk[j];
    }
}

// ---------------------------------------------------------------------------
// K3b: per-bucket: stage slot into LDS (one global read), count node degrees,
// scan, write ofs/oen, place adj IN-PLACE over the pairs slot.
// ---------------------------------------------------------------------------
__launch_bounds__(256)
__global__ void bucket_fill(int* __restrict__ pairs, const int* __restrict__ gcur,
                            int* __restrict__ ofs, int* __restrict__ oen) {
    __shared__ int sP[SLOT];     // 36.9 KB staged edges
    __shared__ int lc[256];
    __shared__ int cur[256];
    const int b    = blockIdx.x;
    const int tid  = threadIdx.x;
    const int base = b * SLOT;
    const int m    = gcur[b];
    for (int i = tid; i < m; i += 256) sP[i] = pairs[base + i];
    lc[tid] = 0;
    __syncthreads();
    // node-degree count (from LDS)
    for (int i = tid; i < m; i += 256) atomicAdd(&lc[sP[i] >> 17], 1);
    __syncthreads();
    // inclusive scan over 256 node degrees
    int v = lc[tid];
    for (int d = 1; d < 256; d <<= 1) {
        int u = (tid >= d) ? lc[tid - d] : 0;
        __syncthreads();
        lc[tid] += u;
        __syncthreads();
    }
    int abs0 = base + lc[tid] - v;        // slot base + exclusive scan
    cur[tid] = abs0;
    const int n = (b << 8) + tid;
    if (n < N_NODES) { ofs[n] = abs0; oen[n] = abs0 + v; }
    __syncthreads();
    // place adj (src only) in-place over the slot; all source data is in LDS
    for (int i = tid; i < m; i += 256) {
        int p = sP[i];
        int r = atomicAdd(&cur[p >> 17], 1);
        pairs[r] = p & 0x1FFFF;
    }
}

// ---------------------------------------------------------------------------
// K4: gather-aggregate (node per wave, 8 rows in flight); emits split-bf16
// h_pre. Launched twice (half the nodes each) for profiler visibility.
// ---------------------------------------------------------------------------
__launch_bounds__(256)
__global__ void gather_aggr(const float* __restrict__ x, const __half* __restrict__ xh,
                            const int* __restrict__ adj, const int* __restrict__ ofs,
                            const int* __restrict__ oen, const float* __restrict__ eps_p,
                            unsigned int* __restrict__ hh, unsigned int* __restrict__ hl,
                            int nbase) {
    int node = nbase + blockIdx.x * 4 + (threadIdx.x >> 6);
    if (node >= N_NODES) return;
    int lane = threadIdx.x & 63;
    int b = ofs[node];
    int e = oen[node];
    const __half2* xp = (const __half2*)xh;
    float ax = 0.f, ay = 0.f;
    int i = b;
    for (; i + 8 <= e; i += 8) {
        int n0 = adj[i],     n1 = adj[i + 1], n2 = adj[i + 2], n3 = adj[i + 3];
        int n4 = adj[i + 4], n5 = adj[i + 5], n6 = adj[i + 6], n7 = adj[i + 7];
        __half2 v0 = xp[(unsigned)n0 * 64u + lane];
        __half2 v1 = xp[(unsigned)n1 * 64u + lane];
        __half2 v2 = xp[(unsigned)n2 * 64u + lane];
        __half2 v3 = xp[(unsigned)n3 * 64u + lane];
        __half2 v4 = xp[(unsigned)n4 * 64u + lane];
        __half2 v5 = xp[(unsigned)n5 * 64u + lane];
        __half2 v6 = xp[(unsigned)n6 * 64u + lane];
        __half2 v7 = xp[(unsigned)n7 * 64u + lane];
        float2 f0 = __half22float2(v0);
        float2 f1 = __half22float2(v1);
        float2 f2 = __half22float2(v2);
        float2 f3 = __half22float2(v3);
        float2 f4 = __half22float2(v4);
        float2 f5 = __half22float2(v5);
        float2 f6 = __half22float2(v6);
        float2 f7 = __half22float2(v7);
        ax += ((f0.x + f1.x) + (f2.x + f3.x)) + ((f4.x + f5.x) + (f6.x + f7.x));
        ay += ((f0.y + f1.y) + (f2.y + f3.y)) + ((f4.y + f5.y) + (f6.y + f7.y));
    }
    for (; i + 4 <= e; i += 4) {
        int n0 = adj[i], n1 = adj[i + 1], n2 = adj[i + 2], n3 = adj[i + 3];
        __half2 v0 = xp[(unsigned)n0 * 64u + lane];
        __half2 v1 = xp[(unsigned)n1 * 64u + lane];
        __half2 v2 = xp[(unsigned)n2 * 64u + lane];
        __half2 v3 = xp[(unsigned)n3 * 64u + lane];
        float2 f0 = __half22float2(v0);
        float2 f1 = __half22float2(v1);
        float2 f2 = __half22float2(v2);
        float2 f3 = __half22float2(v3);
        ax += (f0.x + f1.x) + (f2.x + f3.x);
        ay += (f0.y + f1.y) + (f2.y + f3.y);
    }
    for (; i < e; ++i) {
        __half2 v = xp[(unsigned)adj[i] * 64u + lane];
        float2 f = __half22float2(v);
        ax += f.x;
        ay += f.y;
    }
    float2 xs = ((const float2*)x)[(long long)node * 64 + lane];
    float sc = 2.0f + eps_p[0];
    float ox = fmaf(sc, xs.x, ax);
    float oy = fmaf(sc, xs.y, ay);
    unsigned short hx = bf_hi(ox), hy = bf_hi(oy);
    unsigned short lx = bf_hi(ox - bf_val(hx)), ly = bf_hi(oy - bf_val(hy));
    hh[(long long)node * 64 + lane] = (unsigned)hx | ((unsigned)hy << 16);
    hl[(long long)node * 64 + lane] = (unsigned)lx | ((unsigned)ly << 16);
}

// ---------------------------------------------------------------------------
// K5: h1 = h_pre @ W1^T + b1 (MFMA split-bf16, fp32-accurate) + BN stats
// ---------------------------------------------------------------------------
__launch_bounds__(256)
__global__ void gemm1_mfma(const unsigned short* __restrict__ hh,
                           const unsigned short* __restrict__ hl,
                           const unsigned short* __restrict__ w1h,
                           const unsigned short* __restrict__ w1l,
                           const float* __restrict__ b1, float* __restrict__ h1,
                           float* __restrict__ stats) {
    __shared__ unsigned short sH[TM][136];
    __shared__ unsigned short sL[TM][136];
    __shared__ float sPart[2][4][128];
    const int tid = threadIdx.x;
    const int wv  = tid >> 6;
    const int ln  = tid & 63;
    const int lc  = ln & 15;
    const int qd  = ln >> 4;
    const int row0 = blockIdx.x * TM;

#pragma unroll
    for (int i = 0; i < 4; ++i) {
        int f = tid + 256 * i;
        int r = f >> 4, c8 = f & 15;
        int gr = row0 + r;
        uint4 vh = make_uint4(0, 0, 0, 0), vl = make_uint4(0, 0, 0, 0);
        if (gr < N_NODES) {
            vh = *(const uint4*)(hh + (long long)gr * D + c8 * 8);
            vl = *(const uint4*)(hl + (long long)gr * D + c8 * 8);
        }
        *(uint4*)&sH[r][c8 * 8] = vh;
        *(uint4*)&sL[r][c8 * 8] = vl;
    }
    __syncthreads();

    f32x4 acc[8];
#pragma unroll
    for (int t = 0; t < 8; ++t) acc[t] = (f32x4){0.f, 0.f, 0.f, 0.f};

    const int arow = wv * 16 + lc;
#pragma unroll
    for (int kk = 0; kk < 4; ++kk) {
        short8 ah = *(const short8*)&sH[arow][kk * 32 + qd * 8];
        short8 al = *(const short8*)&sL[arow][kk * 32 + qd * 8];
#pragma unroll
        for (int t = 0; t < 8; ++t) {
            const int woff = (t * 16 + lc) * D + kk * 32 + qd * 8;
            short8 bh = *(const short8*)(w1h + woff);
            short8 bl = *(const short8*)(w1l + woff);
            acc[t] = __builtin_amdgcn_mfma_f32_16x16x32_bf16(ah, bh, acc[t], 0, 0, 0);
            acc[t] = __builtin_amdgcn_mfma_f32_16x16x32_bf16(al, bh, acc[t], 0, 0, 0);
            acc[t] = __builtin_amdgcn_mfma_f32_16x16x32_bf16(ah, bl, acc[t], 0, 0, 0);
        }
    }

    float psum[8], psq[8];
#pragma unroll
    for (int t = 0; t < 8; ++t) {
        int col = t * 16 + lc;
        float bb = b1[col];
        float s = 0.f, q = 0.f;
#pragma unroll
        for (int r = 0; r < 4; ++r) {
            int grow = row0 + wv * 16 + qd * 4 + r;
            if (grow < N_NODES) {
                float o = acc[t][r] + bb;
                h1[(long long)grow * D + col] = o;
                s += o;
                q += o * o;
            }
        }
        psum[t] = s; psq[t] = q;
    }
#pragma unroll
    for (int t = 0; t < 8; ++t) {
        float s = psum[t], q = psq[t];
        s += __shfl_xor(s, 16); s += __shfl_xor(s, 32);
        q += __shfl_xor(q, 16); q += __shfl_xor(q, 32);
        if (qd == 0) { sPart[0][wv][t * 16 + lc] = s; sPart[1][wv][t * 16 + lc] = q; }
    }
    __syncthreads();
    if (tid < 128) {
        float s = sPart[0][0][tid] + sPart[0][1][tid] + sPart[0][2][tid] + sPart[0][3][tid];
        float q = sPart[1][0][tid] + sPart[1][1][tid] + sPart[1][2][tid] + sPart[1][3][tid];
        atomicAdd(&stats[tid], s);
        atomicAdd(&stats[128 + tid], q);
    }
}

// ---------------------------------------------------------------------------
// K6: out = relu(bn(h1)) @ W2^T + b2  (MFMA split-bf16), in-place on d_out
// ---------------------------------------------------------------------------
__launch_bounds__(256)
__global__ void gemm2_mfma(float* __restrict__ h1out,
                           const unsigned short* __restrict__ w2h,
                           const unsigned short* __restrict__ w2l,
                           const float* __restrict__ b2, const float* __restrict__ stats,
                           const float* __restrict__ gamma, const float* __restrict__ beta) {
    __shared__ unsigned short sH[TM][136];
    __shared__ unsigned short sL[TM][136];
    __shared__ float sScale[128];
    __shared__ float sShift[128];
    const int tid = threadIdx.x;
    const int wv  = tid >> 6;
    const int ln  = tid & 63;
    const int lc  = ln & 15;
    const int qd  = ln >> 4;
    const int row0 = blockIdx.x * TM;

    if (tid < 128) {
        float mean = stats[tid] * (1.0f / N_NODES);
        float var  = fmaxf(stats[128 + tid] * (1.0f / N_NODES) - mean * mean, 0.0f);
        float s    = gamma[tid] * rsqrtf(var + BN_EPS);
        sScale[tid] = s;
        sShift[tid] = beta[tid] - mean * s;
    }
    __syncthreads();

#pragma unroll
    for (int i = 0; i < 8; ++i) {
        int f = tid + 256 * i;
        int r = f >> 5, c4 = f & 31;
        int gr = row0 + r;
        float4 v = make_float4(0.f, 0.f, 0.f, 0.f);
        if (gr < N_NODES) {
            v = *(const float4*)(h1out + (long long)gr * D + c4 * 4);
            float4 sc = *(const float4*)&sScale[c4 * 4];
            float4 sh = *(const float4*)&sShift[c4 * 4];
            v.x = fmaxf(0.f, fmaf(v.x, sc.x, sh.x));
            v.y = fmaxf(0.f, fmaf(v.y, sc.y, sh.y));
            v.z = fmaxf(0.f, fmaf(v.z, sc.z, sh.z));
            v.w = fmaxf(0.f, fmaf(v.w, sc.w, sh.w));
        }
        unsigned short h0 = bf_hi(v.x), h1b = bf_hi(v.y), h2 = bf_hi(v.z), h3 = bf_hi(v.w);
        unsigned short l0 = bf_hi(v.x - bf_val(h0)), l1 = bf_hi(v.y - bf_val(h1b));
        unsigned short l2 = bf_hi(v.z - bf_val(h2)), l3 = bf_hi(v.w - bf_val(h3));
        *(uint2*)&sH[r][c4 * 4] = make_uint2((unsigned)h0 | ((unsigned)h1b << 16),
                                             (unsigned)h2 | ((unsigned)h3 << 16));
        *(uint2*)&sL[r][c4 * 4] = make_uint2((unsigned)l0 | ((unsigned)l1 << 16),
                                             (unsigned)l2 | ((unsigned)l3 << 16));
    }
    __syncthreads();

    f32x4 acc[8];
#pragma unroll
    for (int t = 0; t < 8; ++t) acc[t] = (f32x4){0.f, 0.f, 0.f, 0.f};

    const int arow = wv * 16 + lc;
#pragma unroll
    for (int kk = 0; kk < 4; ++kk) {
        short8 ah = *(const short8*)&sH[arow][kk * 32 + qd * 8];
        short8 al = *(const short8*)&sL[arow][kk * 32 + qd * 8];
#pragma unroll
        for (int t = 0; t < 8; ++t) {
            const int woff = (t * 16 + lc) * D + kk * 32 + qd * 8;
            short8 bh = *(const short8*)(w2h + woff);
            short8 bl = *(const short8*)(w2l + woff);
            acc[t] = __builtin_amdgcn_mfma_f32_16x16x32_bf16(ah, bh, acc[t], 0, 0, 0);
            acc[t] = __builtin_amdgcn_mfma_f32_16x16x32_bf16(al, bh, acc[t], 0, 0, 0);
            acc[t] = __builtin_amdgcn_mfma_f32_16x16x32_bf16(ah, bl, acc[t], 0, 0, 0);
        }
    }

#pragma unroll
    for (int t = 0; t < 8; ++t) {
        int col = t * 16 + lc;
        float bb = b2[col];
#pragma unroll
        for (int r = 0; r < 4; ++r) {
            int grow = row0 + wv * 16 + qd * 4 + r;
            if (grow < N_NODES) {
                h1out[(long long)grow * D + col] = acc[t][r] + bb;
            }
        }
    }
}

// ---------------------------------------------------------------------------
extern "C" void kernel_launch(void* const* d_in, const int* in_sizes, int n_in,
                              void* d_out, int out_size, void* d_ws, size_t ws_size,
                              hipStream_t stream) {
    const float* x     = (const float*)d_in[0];
    const int*   ei    = (const int*)d_in[1];
    const float* eps_p = (const float*)d_in[2];
    const float* W1    = (const float*)d_in[3];
    const float* b1    = (const float*)d_in[4];
    const float* gamma = (const float*)d_in[5];
    const float* beta  = (const float*)d_in[6];
    const float* W2    = (const float*)d_in[7];
    const float* b2    = (const float*)d_in[8];

    // workspace layout (~52.3 MB)
    unsigned int* hh  = (unsigned int*)d_ws;                  // N*64 uints: hpre hi
    unsigned int* hl  = hh + (long long)N_NODES * 64;         // hpre lo
    float* stats = (float*)(hl + (long long)N_NODES * 64);    // 512 floats
    int*   gcur  = (int*)(stats + 512);                       // 512 ints (zeroed w/ stats)
    int*   ofs   = gcur + 512;                                // N ints
    int*   oen   = ofs + N_NODES;                             // N ints
    unsigned short* w1h = (unsigned short*)(oen + N_NODES);
    unsigned short* w1l = w1h + 16384;
    unsigned short* w2h = w1l + 16384;
    unsigned short* w2l = w2h + 16384;

    float* out   = (float*)d_out;                             // h1 scratch + final out
    __half* xh   = (__half*)d_out;                            // fp16 mirror: d_out[0:25.6MB]
    int*  pairs  = (int*)((char*)d_out + (size_t)N_NODES * 256);  // slot region, 14.4MB
    int*  adj    = pairs;                                     // adj aliases pairs (in-place)

    {   // K0: fp16 convert + zero stats/gcur + split W
        int grid = (N_NODES * (D / 4) + 255) / 256;
        convert_zero<<<grid, 256, 0, stream>>>(x, xh, (int*)stats,
                                               W1, W2, w1h, w1l, w2h, w2l);
    }
    {   // K3a: coarse-bucket partition into fixed slots
        int grid = (2 * EDGES + L1TILE - 1) / L1TILE;
        partition_pairs<<<grid, 256, 0, stream>>>(ei, gcur, pairs);
    }
    {   // K3b: per-bucket LDS-staged count+scan+place -> ofs/oen, adj in-place
        bucket_fill<<<NB, 256, 0, stream>>>(pairs, gcur, ofs, oen);
    }
    {   // K4: gather-aggregate (two half-launches for profiler visibility)
        int half = N_NODES / 2;                               // 50000
        int grid = (half + 3) / 4;
        gather_aggr<<<grid, 256, 0, stream>>>(x, xh, adj, ofs, oen, eps_p, hh, hl, 0);
        int grid2 = (N_NODES - half + 3) / 4;
        gather_aggr<<<grid2, 256, 0, stream>>>(x, xh, adj, ofs, oen, eps_p, hh, hl, half);
    }
    {   // K5: MFMA GEMM1 + BN stats (h1 -> d_out)
        int grid = (N_NODES + TM - 1) / TM;
        gemm1_mfma<<<grid, 256, 0, stream>>>((const unsigned short*)hh, (const unsigned short*)hl,
                                             w1h, w1l, b1, out, stats);
    }
    {   // K6: BN finalize + ReLU + MFMA GEMM2, in-place on d_out
        int grid = (N_NODES + TM - 1) / TM;
        gemm2_mfma<<<grid, 256, 0, stream>>>(out, w2h, w2l, b2, stats, gamma, beta);
    }
}

// Round 4
// 350.764 us; speedup vs baseline: 1.7787x; 1.3198x over previous
//
#include <hip/hip_runtime.h>
#include <hip/hip_fp16.h>

#define N_NODES 100000
#define EDGES   1600000
#define D       128
#define BN_EPS  1e-5f
#define TM      64                        // rows per GEMM tile
#define NT      ((N_NODES + TM - 1) / TM) // 1563 row tiles
#define GGRID   782                       // gemm grid: 2 tiles/block, ~3 blocks/CU
#define NB      ((N_NODES + 255) >> 8)    // 391 coarse buckets (256 nodes each)
#define SLOT    9216                      // fixed slot per bucket: mean 8192 + 11 sigma
#define L1E     16                        // slots per thread in partition pass
#define L1TILE  (256 * L1E)               // 4096 edges per tile

typedef __attribute__((ext_vector_type(8))) short short8;
typedef __attribute__((ext_vector_type(4))) float f32x4;

__device__ __forceinline__ unsigned short bf_hi(float f) {
    unsigned u = __float_as_uint(f);
    unsigned t = u + 0x7FFF + ((u >> 16) & 1);
    return (unsigned short)(t >> 16);
}
__device__ __forceinline__ float bf_val(unsigned short h) {
    return __uint_as_float(((unsigned)h) << 16);
}

// ---------------------------------------------------------------------------
// K0: convert x -> fp16 mirror; zero stats(2048f)+gcur(512i); split W1/W2
// ---------------------------------------------------------------------------
__global__ void convert_zero(const float* __restrict__ x, __half* __restrict__ xh,
                             int* __restrict__ zbase,
                             const float* __restrict__ W1, const float* __restrict__ W2,
                             unsigned short* __restrict__ w1h, unsigned short* __restrict__ w1l,
                             unsigned short* __restrict__ w2h, unsigned short* __restrict__ w2l) {
    int gid = blockIdx.x * blockDim.x + threadIdx.x;
    if (gid < 2560) zbase[gid] = 0;
    if (gid < 16384) {
        float f = W1[gid];
        unsigned short h = bf_hi(f);
        w1h[gid] = h;
        w1l[gid] = bf_hi(f - bf_val(h));
    } else if (gid < 32768) {
        int j = gid - 16384;
        float f = W2[j];
        unsigned short h = bf_hi(f);
        w2h[j] = h;
        w2l[j] = bf_hi(f - bf_val(h));
    }
    const int n4 = N_NODES * (D / 4);
    if (gid < n4) {
        float4 v = ((const float4*)x)[gid];
        __half2 h0 = __float22half2_rn(make_float2(v.x, v.y));
        __half2 h1 = __float22half2_rn(make_float2(v.z, v.w));
        ((__half2*)xh)[(long long)gid * 2 + 0] = h0;
        ((__half2*)xh)[(long long)gid * 2 + 1] = h1;
    }
}

// ---------------------------------------------------------------------------
// K3a: coarse-bucket partition into fixed slots.
// pairs entry: (local_dst<<17) | src   (src < 2^17, local_dst < 256)
// ---------------------------------------------------------------------------
__launch_bounds__(256)
__global__ void partition_pairs(const int* __restrict__ ei, int* __restrict__ gcur,
                                int* __restrict__ pairs) {
    __shared__ int cnt[NB];
    __shared__ int cbase[NB];
    const int tid = threadIdx.x;
    for (int i = tid; i < NB; i += 256) cnt[i] = 0;
    __syncthreads();

    int bb[L1E], rr[L1E], pk[L1E];
    const int t0 = blockIdx.x * L1TILE + tid;
#pragma unroll
    for (int j = 0; j < L1E; ++j) {
        int t = t0 + j * 256;
        bb[j] = -1;
        if (t < 2 * EDGES) {
            int vl = ei[t];
            int pt = (t < EDGES) ? t + EDGES : t - EDGES;
            int nd = ei[pt];
            bb[j] = nd >> 8;
            pk[j] = ((nd & 255) << 17) | vl;
            rr[j] = atomicAdd(&cnt[bb[j]], 1);
        }
    }
    __syncthreads();
    for (int i = tid; i < NB; i += 256) {
        int c = cnt[i];
        cbase[i] = c ? (i * SLOT + atomicAdd(&gcur[i], c)) : 0;
    }
    __syncthreads();
#pragma unroll
    for (int j = 0; j < L1E; ++j) {
        if (bb[j] >= 0) pairs[cbase[bb[j]] + rr[j]] = pk[j];
    }
}

// ---------------------------------------------------------------------------
// K3b: per-bucket: stage slot into LDS, count node degrees, scan, write
// ofs/oen, place adj IN-PLACE over the pairs slot.
// ---------------------------------------------------------------------------
__launch_bounds__(256)
__global__ void bucket_fill(int* __restrict__ pairs, const int* __restrict__ gcur,
                            int* __restrict__ ofs, int* __restrict__ oen) {
    __shared__ int sP[SLOT];     // 36.9 KB staged edges
    __shared__ int lc[256];
    __shared__ int cur[256];
    const int b    = blockIdx.x;
    const int tid  = threadIdx.x;
    const int base = b * SLOT;
    const int m    = min(gcur[b], SLOT);   // clamp: LDS-overflow guard
    for (int i = tid; i < m; i += 256) sP[i] = pairs[base + i];
    lc[tid] = 0;
    __syncthreads();
    for (int i = tid; i < m; i += 256) atomicAdd(&lc[sP[i] >> 17], 1);
    __syncthreads();
    int v = lc[tid];
    for (int d = 1; d < 256; d <<= 1) {
        int u = (tid >= d) ? lc[tid - d] : 0;
        __syncthreads();
        lc[tid] += u;
        __syncthreads();
    }
    int abs0 = base + lc[tid] - v;
    cur[tid] = abs0;
    const int n = (b << 8) + tid;
    if (n < N_NODES) { ofs[n] = abs0; oen[n] = abs0 + v; }
    __syncthreads();
    for (int i = tid; i < m; i += 256) {
        int p = sP[i];
        int r = atomicAdd(&cur[p >> 17], 1);
        pairs[r] = p & 0x1FFFF;
    }
}

// ---------------------------------------------------------------------------
// K4: gather-aggregate (node per wave, 8 rows in flight); split-bf16 out
// ---------------------------------------------------------------------------
__launch_bounds__(256)
__global__ void gather_aggr(const float* __restrict__ x, const __half* __restrict__ xh,
                            const int* __restrict__ adj, const int* __restrict__ ofs,
                            const int* __restrict__ oen, const float* __restrict__ eps_p,
                            unsigned int* __restrict__ hh, unsigned int* __restrict__ hl) {
    int node = blockIdx.x * 4 + (threadIdx.x >> 6);
    if (node >= N_NODES) return;
    int lane = threadIdx.x & 63;
    int b = ofs[node];
    int e = oen[node];
    const __half2* xp = (const __half2*)xh;
    float ax = 0.f, ay = 0.f;
    int i = b;
    for (; i + 8 <= e; i += 8) {
        int n0 = adj[i],     n1 = adj[i + 1], n2 = adj[i + 2], n3 = adj[i + 3];
        int n4 = adj[i + 4], n5 = adj[i + 5], n6 = adj[i + 6], n7 = adj[i + 7];
        __half2 v0 = xp[(unsigned)n0 * 64u + lane];
        __half2 v1 = xp[(unsigned)n1 * 64u + lane];
        __half2 v2 = xp[(unsigned)n2 * 64u + lane];
        __half2 v3 = xp[(unsigned)n3 * 64u + lane];
        __half2 v4 = xp[(unsigned)n4 * 64u + lane];
        __half2 v5 = xp[(unsigned)n5 * 64u + lane];
        __half2 v6 = xp[(unsigned)n6 * 64u + lane];
        __half2 v7 = xp[(unsigned)n7 * 64u + lane];
        float2 f0 = __half22float2(v0);
        float2 f1 = __half22float2(v1);
        float2 f2 = __half22float2(v2);
        float2 f3 = __half22float2(v3);
        float2 f4 = __half22float2(v4);
        float2 f5 = __half22float2(v5);
        float2 f6 = __half22float2(v6);
        float2 f7 = __half22float2(v7);
        ax += ((f0.x + f1.x) + (f2.x + f3.x)) + ((f4.x + f5.x) + (f6.x + f7.x));
        ay += ((f0.y + f1.y) + (f2.y + f3.y)) + ((f4.y + f5.y) + (f6.y + f7.y));
    }
    for (; i + 4 <= e; i += 4) {
        int n0 = adj[i], n1 = adj[i + 1], n2 = adj[i + 2], n3 = adj[i + 3];
        __half2 v0 = xp[(unsigned)n0 * 64u + lane];
        __half2 v1 = xp[(unsigned)n1 * 64u + lane];
        __half2 v2 = xp[(unsigned)n2 * 64u + lane];
        __half2 v3 = xp[(unsigned)n3 * 64u + lane];
        float2 f0 = __half22float2(v0);
        float2 f1 = __half22float2(v1);
        float2 f2 = __half22float2(v2);
        float2 f3 = __half22float2(v3);
        ax += (f0.x + f1.x) + (f2.x + f3.x);
        ay += (f0.y + f1.y) + (f2.y + f3.y);
    }
    for (; i < e; ++i) {
        __half2 v = xp[(unsigned)adj[i] * 64u + lane];
        float2 f = __half22float2(v);
        ax += f.x;
        ay += f.y;
    }
    float2 xs = ((const float2*)x)[(long long)node * 64 + lane];
    float sc = 2.0f + eps_p[0];
    float ox = fmaf(sc, xs.x, ax);
    float oy = fmaf(sc, xs.y, ay);
    unsigned short hx = bf_hi(ox), hy = bf_hi(oy);
    unsigned short lx = bf_hi(ox - bf_val(hx)), ly = bf_hi(oy - bf_val(hy));
    hh[(long long)node * 64 + lane] = (unsigned)hx | ((unsigned)hy << 16);
    hl[(long long)node * 64 + lane] = (unsigned)lx | ((unsigned)ly << 16);
}

// ---------------------------------------------------------------------------
// K5: h1 = h_pre @ W1^T + b1 (persistent-B MFMA, grid-strided, prefetch) +
// register-accumulated BN stats flushed to 8 replicas at kernel end.
// Wave wv owns cols [wv*32, wv*32+32).
// ---------------------------------------------------------------------------
__launch_bounds__(256)
__global__ void gemm1_mfma(const unsigned short* __restrict__ hh,
                           const unsigned short* __restrict__ hl,
                           const unsigned short* __restrict__ w1h,
                           const unsigned short* __restrict__ w1l,
                           const float* __restrict__ b1, float* __restrict__ h1,
                           float* __restrict__ stats) {
    __shared__ unsigned short sH[TM][136];
    __shared__ unsigned short sL[TM][136];
    const int tid = threadIdx.x;
    const int wv  = tid >> 6;
    const int ln  = tid & 63;
    const int lc  = ln & 15;
    const int qd  = ln >> 4;
    const int sr  = tid >> 4;      // staging row base (0..15)
    const int sc8 = tid & 15;      // staging 8-short chunk

    // persistent B fragments (held whole kernel): kk(4) x tl(2) x {hi,lo}
    short8 Bh[4][2], Bl[4][2];
#pragma unroll
    for (int kk = 0; kk < 4; ++kk)
#pragma unroll
        for (int tl = 0; tl < 2; ++tl) {
            int woff = (wv * 32 + tl * 16 + lc) * D + kk * 32 + qd * 8;
            Bh[kk][tl] = *(const short8*)(w1h + woff);
            Bl[kk][tl] = *(const short8*)(w1l + woff);
        }
    float bb[2];
    bb[0] = b1[wv * 32 + lc];
    bb[1] = b1[wv * 32 + 16 + lc];

    float sAcc[2] = {0.f, 0.f}, qAcc[2] = {0.f, 0.f};

    uint4 vh[4], vl[4];
    int tile = blockIdx.x;
    // prefetch first tile
#pragma unroll
    for (int i = 0; i < 4; ++i) {
        int gr = tile * TM + sr + i * 16;
        vh[i] = make_uint4(0, 0, 0, 0);
        vl[i] = make_uint4(0, 0, 0, 0);
        if (gr < N_NODES) {
            vh[i] = *(const uint4*)(hh + (long long)gr * D + sc8 * 8);
            vl[i] = *(const uint4*)(hl + (long long)gr * D + sc8 * 8);
        }
    }

    while (tile < NT) {
        // write staged regs to LDS
#pragma unroll
        for (int i = 0; i < 4; ++i) {
            *(uint4*)&sH[sr + i * 16][sc8 * 8] = vh[i];
            *(uint4*)&sL[sr + i * 16][sc8 * 8] = vl[i];
        }
        __syncthreads();
        int nxt = tile + GGRID;
        if (nxt < NT) {   // prefetch next tile (latency hides under compute)
#pragma unroll
            for (int i = 0; i < 4; ++i) {
                int gr = nxt * TM + sr + i * 16;
                vh[i] = make_uint4(0, 0, 0, 0);
                vl[i] = make_uint4(0, 0, 0, 0);
                if (gr < N_NODES) {
                    vh[i] = *(const uint4*)(hh + (long long)gr * D + sc8 * 8);
                    vl[i] = *(const uint4*)(hl + (long long)gr * D + sc8 * 8);
                }
            }
        }

        f32x4 acc[4][2];
#pragma unroll
        for (int m = 0; m < 4; ++m)
#pragma unroll
            for (int tl = 0; tl < 2; ++tl) acc[m][tl] = (f32x4){0.f, 0.f, 0.f, 0.f};

#pragma unroll
        for (int kk = 0; kk < 4; ++kk) {
#pragma unroll
            for (int m = 0; m < 4; ++m) {
                short8 ah = *(const short8*)&sH[m * 16 + lc][kk * 32 + qd * 8];
                short8 al = *(const short8*)&sL[m * 16 + lc][kk * 32 + qd * 8];
#pragma unroll
                for (int tl = 0; tl < 2; ++tl) {
                    acc[m][tl] = __builtin_amdgcn_mfma_f32_16x16x32_bf16(ah, Bh[kk][tl], acc[m][tl], 0, 0, 0);
                    acc[m][tl] = __builtin_amdgcn_mfma_f32_16x16x32_bf16(al, Bh[kk][tl], acc[m][tl], 0, 0, 0);
                    acc[m][tl] = __builtin_amdgcn_mfma_f32_16x16x32_bf16(ah, Bl[kk][tl], acc[m][tl], 0, 0, 0);
                }
            }
        }

        const int row0 = tile * TM;
#pragma unroll
        for (int m = 0; m < 4; ++m)
#pragma unroll
            for (int tl = 0; tl < 2; ++tl) {
                int col = wv * 32 + tl * 16 + lc;
#pragma unroll
                for (int r = 0; r < 4; ++r) {
                    int grow = row0 + m * 16 + qd * 4 + r;
                    if (grow < N_NODES) {
                        float o = acc[m][tl][r] + bb[tl];
                        h1[(long long)grow * D + col] = o;
                        sAcc[tl] += o;
                        qAcc[tl] += o * o;
                    }
                }
            }
        __syncthreads();
        tile = nxt;
    }

    // flush stats: reduce over qd, one atomic per (col, s/q) into replica
    const int rep = blockIdx.x & 7;
#pragma unroll
    for (int tl = 0; tl < 2; ++tl) {
        float s = sAcc[tl], q = qAcc[tl];
        s += __shfl_xor(s, 16); s += __shfl_xor(s, 32);
        q += __shfl_xor(q, 16); q += __shfl_xor(q, 32);
        if (qd == 0) {
            int col = wv * 32 + tl * 16 + lc;
            atomicAdd(&stats[rep * 256 + col], s);
            atomicAdd(&stats[rep * 256 + 128 + col], q);
        }
    }
}

// ---------------------------------------------------------------------------
// K6: out = relu(bn(h1)) @ W2^T + b2  (persistent-B MFMA, grid-strided,
// prefetch), in-place on d_out. Reduces the 8 stat replicas in prologue.
// ---------------------------------------------------------------------------
__launch_bounds__(256)
__global__ void gemm2_mfma(float* __restrict__ h1out,
                           const unsigned short* __restrict__ w2h,
                           const unsigned short* __restrict__ w2l,
                           const float* __restrict__ b2, const float* __restrict__ stats,
                           const float* __restrict__ gamma, const float* __restrict__ beta) {
    __shared__ unsigned short sH[TM][136];
    __shared__ unsigned short sL[TM][136];
    __shared__ float sScale[128];
    __shared__ float sShift[128];
    const int tid = threadIdx.x;
    const int wv  = tid >> 6;
    const int ln  = tid & 63;
    const int lc  = ln & 15;
    const int qd  = ln >> 4;
    const int sr  = tid >> 5;      // staging row base (0..7)
    const int sc4 = tid & 31;      // staging float4 chunk

    if (tid < 128) {
        float s = 0.f, q = 0.f;
#pragma unroll
        for (int r = 0; r < 8; ++r) {
            s += stats[r * 256 + tid];
            q += stats[r * 256 + 128 + tid];
        }
        float mean = s * (1.0f / N_NODES);
        float var  = fmaxf(q * (1.0f / N_NODES) - mean * mean, 0.0f);
        float sc   = gamma[tid] * rsqrtf(var + BN_EPS);
        sScale[tid] = sc;
        sShift[tid] = beta[tid] - mean * sc;
    }

    short8 Bh[4][2], Bl[4][2];
#pragma unroll
    for (int kk = 0; kk < 4; ++kk)
#pragma unroll
        for (int tl = 0; tl < 2; ++tl) {
            int woff = (wv * 32 + tl * 16 + lc) * D + kk * 32 + qd * 8;
            Bh[kk][tl] = *(const short8*)(w2h + woff);
            Bl[kk][tl] = *(const short8*)(w2l + woff);
        }
    float bb[2];
    bb[0] = b2[wv * 32 + lc];
    bb[1] = b2[wv * 32 + 16 + lc];

    __syncthreads();   // sScale/sShift ready

    float4 pf[8];
    int tile = blockIdx.x;
#pragma unroll
    for (int i = 0; i < 8; ++i) {
        int gr = tile * TM + sr + i * 8;
        pf[i] = make_float4(0.f, 0.f, 0.f, 0.f);
        if (gr < N_NODES)
            pf[i] = *(const float4*)(h1out + (long long)gr * D + sc4 * 4);
    }

    while (tile < NT) {
        // BN + relu + split-bf16 + LDS write
        float4 scv = *(const float4*)&sScale[sc4 * 4];
        float4 shv = *(const float4*)&sShift[sc4 * 4];
#pragma unroll
        for (int i = 0; i < 8; ++i) {
            int gr = tile * TM + sr + i * 8;
            float4 v = pf[i];
            if (gr < N_NODES) {
                v.x = fmaxf(0.f, fmaf(v.x, scv.x, shv.x));
                v.y = fmaxf(0.f, fmaf(v.y, scv.y, shv.y));
                v.z = fmaxf(0.f, fmaf(v.z, scv.z, shv.z));
                v.w = fmaxf(0.f, fmaf(v.w, scv.w, shv.w));
            } else {
                v = make_float4(0.f, 0.f, 0.f, 0.f);
            }
            unsigned short h0 = bf_hi(v.x), h1b = bf_hi(v.y), h2 = bf_hi(v.z), h3 = bf_hi(v.w);
            unsigned short l0 = bf_hi(v.x - bf_val(h0)), l1 = bf_hi(v.y - bf_val(h1b));
            unsigned short l2 = bf_hi(v.z - bf_val(h2)), l3 = bf_hi(v.w - bf_val(h3));
            int r = sr + i * 8;
            *(uint2*)&sH[r][sc4 * 4] = make_uint2((unsigned)h0 | ((unsigned)h1b << 16),
                                                  (unsigned)h2 | ((unsigned)h3 << 16));
            *(uint2*)&sL[r][sc4 * 4] = make_uint2((unsigned)l0 | ((unsigned)l1 << 16),
                                                  (unsigned)l2 | ((unsigned)l3 << 16));
        }
        __syncthreads();
        int nxt = tile + GGRID;
        if (nxt < NT) {
#pragma unroll
            for (int i = 0; i < 8; ++i) {
                int gr = nxt * TM + sr + i * 8;
                pf[i] = make_float4(0.f, 0.f, 0.f, 0.f);
                if (gr < N_NODES)
                    pf[i] = *(const float4*)(h1out + (long long)gr * D + sc4 * 4);
            }
        }

        f32x4 acc[4][2];
#pragma unroll
        for (int m = 0; m < 4; ++m)
#pragma unroll
            for (int tl = 0; tl < 2; ++tl) acc[m][tl] = (f32x4){0.f, 0.f, 0.f, 0.f};

#pragma unroll
        for (int kk = 0; kk < 4; ++kk) {
#pragma unroll
            for (int m = 0; m < 4; ++m) {
                short8 ah = *(const short8*)&sH[m * 16 + lc][kk * 32 + qd * 8];
                short8 al = *(const short8*)&sL[m * 16 + lc][kk * 32 + qd * 8];
#pragma unroll
                for (int tl = 0; tl < 2; ++tl) {
                    acc[m][tl] = __builtin_amdgcn_mfma_f32_16x16x32_bf16(ah, Bh[kk][tl], acc[m][tl], 0, 0, 0);
                    acc[m][tl] = __builtin_amdgcn_mfma_f32_16x16x32_bf16(al, Bh[kk][tl], acc[m][tl], 0, 0, 0);
                    acc[m][tl] = __builtin_amdgcn_mfma_f32_16x16x32_bf16(ah, Bl[kk][tl], acc[m][tl], 0, 0, 0);
                }
            }
        }

        const int row0 = tile * TM;
#pragma unroll
        for (int m = 0; m < 4; ++m)
#pragma unroll
            for (int tl = 0; tl < 2; ++tl) {
                int col = wv * 32 + tl * 16 + lc;
#pragma unroll
                for (int r = 0; r < 4; ++r) {
                    int grow = row0 + m * 16 + qd * 4 + r;
                    if (grow < N_NODES)
                        h1out[(long long)grow * D + col] = acc[m][tl][r] + bb[tl];
                }
            }
        __syncthreads();
        tile = nxt;
    }
}

// ---------------------------------------------------------------------------
extern "C" void kernel_launch(void* const* d_in, const int* in_sizes, int n_in,
                              void* d_out, int out_size, void* d_ws, size_t ws_size,
                              hipStream_t stream) {
    const float* x     = (const float*)d_in[0];
    const int*   ei    = (const int*)d_in[1];
    const float* eps_p = (const float*)d_in[2];
    const float* W1    = (const float*)d_in[3];
    const float* b1    = (const float*)d_in[4];
    const float* gamma = (const float*)d_in[5];
    const float* beta  = (const float*)d_in[6];
    const float* W2    = (const float*)d_in[7];
    const float* b2    = (const float*)d_in[8];

    // workspace layout (~52.5 MB)
    unsigned int* hh  = (unsigned int*)d_ws;                  // N*64 uints: hpre hi
    unsigned int* hl  = hh + (long long)N_NODES * 64;         // hpre lo
    float* stats = (float*)(hl + (long long)N_NODES * 64);    // 2048 floats (8 replicas)
    int*   gcur  = (int*)(stats + 2048);                      // 512 ints (zeroed w/ stats)
    int*   ofs   = gcur + 512;                                // N ints
    int*   oen   = ofs + N_NODES;                             // N ints
    unsigned short* w1h = (unsigned short*)(oen + N_NODES);
    unsigned short* w1l = w1h + 16384;
    unsigned short* w2h = w1l + 16384;
    unsigned short* w2l = w2h + 16384;

    float* out   = (float*)d_out;                             // h1 scratch + final out
    __half* xh   = (__half*)d_out;                            // fp16 mirror: d_out[0:25.6MB]
    int*  pairs  = (int*)((char*)d_out + (size_t)N_NODES * 256);  // slot region, 14.4MB
    int*  adj    = pairs;                                     // adj aliases pairs (in-place)

    {   // K0: fp16 convert + zero stats/gcur + split W
        int grid = (N_NODES * (D / 4) + 255) / 256;
        convert_zero<<<grid, 256, 0, stream>>>(x, xh, (int*)stats,
                                               W1, W2, w1h, w1l, w2h, w2l);
    }
    {   // K3a: coarse-bucket partition into fixed slots
        int grid = (2 * EDGES + L1TILE - 1) / L1TILE;
        partition_pairs<<<grid, 256, 0, stream>>>(ei, gcur, pairs);
    }
    {   // K3b: per-bucket LDS-staged count+scan+place -> ofs/oen, adj in-place
        bucket_fill<<<NB, 256, 0, stream>>>(pairs, gcur, ofs, oen);
    }
    {   // K4: gather-aggregate
        int grid = (N_NODES + 3) / 4;
        gather_aggr<<<grid, 256, 0, stream>>>(x, xh, adj, ofs, oen, eps_p, hh, hl);
    }
    {   // K5: persistent-B MFMA GEMM1 + BN stats (h1 -> d_out)
        gemm1_mfma<<<GGRID, 256, 0, stream>>>((const unsigned short*)hh, (const unsigned short*)hl,
                                              w1h, w1l, b1, out, stats);
    }
    {   // K6: BN finalize + ReLU + persistent-B MFMA GEMM2, in-place on d_out
        gemm2_mfma<<<GGRID, 256, 0, stream>>>(out, w2h, w2l, b2, stats, gamma, beta);
    }
}